// Round 9
// baseline (189.437 us; speedup 1.0000x reference)
//
#include <hip/hip_runtime.h>

// Problem constants
#define T_SEQ 2048
#define C_DIM 1024
#define H_NUM 16
#define H_D   64
#define B_NUM 4
#define M_ROWS 8192   // B*T

typedef __attribute__((ext_vector_type(4))) float f32x4;
typedef __attribute__((ext_vector_type(8))) short bf16x8;   // 8 bf16 = 4 VGPRs

__device__ __forceinline__ unsigned short f2bf(float f) {
  union { float f; unsigned int u; } a;
  a.f = f;
  unsigned int u = a.u;
  u += 0x7fffu + ((u >> 16) & 1u);   // RNE
  return (unsigned short)(u >> 16);
}

__device__ __forceinline__ unsigned int fbits(float f) {
  union { float f; unsigned int u; } a; a.f = f; return a.u;
}

// pack the high halves (bf16-truncate) of two f32 into one u32: {hi(b), hi(a)}
__device__ __forceinline__ unsigned int pack_hi(float a, float b) {
#if __has_builtin(__builtin_amdgcn_perm)
  return __builtin_amdgcn_perm(fbits(b), fbits(a), 0x07060302u);  // 1 VALU op
#else
  return (fbits(b) & 0xffff0000u) | (fbits(a) >> 16);
#endif
}

// async global->LDS, 16B per lane; LDS dest = wave-uniform base + lane*16
__device__ __forceinline__ void gload_lds16(const unsigned short* g, unsigned short* l) {
  __builtin_amdgcn_global_load_lds(
      (const __attribute__((address_space(1))) unsigned int*)g,
      (__attribute__((address_space(3))) unsigned int*)l, 16, 0, 0);
}

// ---------------------------------------------------------------- fused cast fp32 -> bf16
__global__ __launch_bounds__(256) void cast_all_kernel(const float* __restrict__ x,
                                                       const float* __restrict__ wa,
                                                       const float* __restrict__ wp,
                                                       unsigned short* __restrict__ xb,
                                                       unsigned short* __restrict__ wab,
                                                       unsigned short* __restrict__ wpb) {
  int i = blockIdx.x * 256 + threadIdx.x;
  const float* src;
  unsigned short* dst;
  int off;
  if (i < 2097152) {           // x: 8192*1024/4
    src = x; dst = xb; off = i;
  } else if (i < 2883584) {    // w_attn: 3072*1024/4
    src = wa; dst = wab; off = i - 2097152;
  } else {                     // w_proj: 1024*1024/4
    src = wp; dst = wpb; off = i - 2883584;
  }
  float4 v = reinterpret_cast<const float4*>(src)[off];
  ushort4 o;
  o.x = f2bf(v.x); o.y = f2bf(v.y); o.z = f2bf(v.z); o.w = f2bf(v.w);
  reinterpret_cast<ushort4*>(dst)[off] = o;
}

// ---------------------------------------------------------------- GEMM0 (QKV) -- 8-phase
// Round 9: faithful 8-phase schedule (guide §5 template / T3+T4+T5) with a
// DERIVED lifetime-proven stage plan (r2's improvised geometry is what
// failed). The 2-phase family is closed: per-block staging rate ~4.4 B/cy
// invariant to pipelining (r1), block size (r7), tile (r0/r4) -> 563 TF
// max. m248 measured 848 TF at K=1024 with this schedule.
//
// Geometry: BM=256 x BN=192, BK=64, 8 waves (2M x 4N), per-wave C 128x48
// (acc[8][3] = 96 regs; ~170 live < 256 @ launch_bounds(512,2) -- r2
// measured this envelope clean). Grid 32x16 = 512 = 2 exact rounds at
// 1 blk/CU. LDS 2 x (A 32KB + B 24KB) = 112KB (r2 ran 114688 on HW).
//
// Half-tiles split BY K (A-k0/A-k1 16KB, B-k0/B-k1 12KB): phase (ks,ch)
// reads only kslot ks -> a kslot region is DEAD after phase 2ks+1, so
// staging kt+2's k0 into the CURRENT buffer at p2/p3 is legal, and every
// stage has a 5-6 phase issue->use lead (counted-vmcnt prerequisite).
// Stage plan per K-tile kt:  p0: A(kt+1,k1)  p1: B(kt+1,k1)
//                            p2: A(kt+2,k0)  p3: B(kt+2,k0)
// One vmcnt(3) per K-tile at p3 (retires exactly through kt+1's stages,
// leaves the 2 newest in flight); vmcnt(0) only at kt=KT-2.
// LDS layout/swizzle: r1's 2-rows-per-128B scheme (slot8 = ((r&1)<<2|k16)
// ^ (p&7)), measured 0 bank conflicts on HW; linear LDS dest +
// pre-swizzled global source (rule #21).
__global__ __launch_bounds__(512, 2) void gemm_qkv8_kernel(
    const unsigned short* __restrict__ A,
    const unsigned short* __restrict__ Bw,
    unsigned short* __restrict__ q_ws,
    unsigned short* __restrict__ k_ws,
    unsigned short* __restrict__ v_ws) {
  constexpr int KK = 1024;
  constexpr int KT = KK / 64;            // 16 K-tiles

  // regions (halfwords): A-k0 @0 (8192), A-k1 @8192, B-k0 @16384 (6144), B-k1 @22528
  __shared__ __align__(16) unsigned short lds[2][28672];   // 112KB

  const int bid = blockIdx.x;            // NWG = 512, %8 == 0
  const int logical = (bid & 7) * 64 + (bid >> 3);
  const int rb = logical >> 4, cb = logical & 15;   // 32 x 16

  const int t = threadIdx.x;
  const int w = t >> 6, l = t & 63;
  const int wr = w >> 2, wc = w & 3;     // 2M x 4N wave grid
  const int lq = l & 15, lg = l >> 4;

  const size_t a_base = (size_t)(rb * 256) * KK;
  const size_t b_base = (size_t)(cb * 192) * KK;

  // ---- staging: chunk c -> LDS phys (p=c>>3, slot8=c&7); source row/k16 from
  // inverse swizzle sp = (c&7)^(p&7): r = (p<<1)|(sp>>2), k16 = sp&3.
  // A region: 1024 chunks (2/thread). B region: 768 chunks (2 for t<256, else 1).
  const unsigned short* aSrc[2];
  int aOffL[2];
#pragma unroll
  for (int i = 0; i < 2; ++i) {
    int c = t + 512 * i;
    int p = c >> 3, sp = (c & 7) ^ (p & 7);
    int r = (p << 1) | (sp >> 2);
    aSrc[i] = A + a_base + (size_t)r * KK + (sp & 3) * 8;
    aOffL[i] = c * 8;
  }
  const unsigned short* bSrc[2];
  int bOffL[2];
#pragma unroll
  for (int i = 0; i < 2; ++i) {
    int c = t + 512 * i;
    int cc = (c < 768) ? c : 0;          // dummy for inactive slot
    int p = cc >> 3, sp = (cc & 7) ^ (p & 7);
    int r = (p << 1) | (sp >> 2);
    bSrc[i] = Bw + b_base + (size_t)r * KK + (sp & 3) * 8;
    bOffL[i] = cc * 8;
  }

#define STAGE_A(KT_, KS)                                                      \
  { unsigned short* d_ = &lds[(KT_) & 1][(KS) * 8192];                        \
    _Pragma("unroll")                                                         \
    for (int i_ = 0; i_ < 2; ++i_)                                            \
      gload_lds16(aSrc[i_] + (KT_) * 64 + (KS) * 32, d_ + aOffL[i_]); }

#define STAGE_B(KT_, KS)                                                      \
  { unsigned short* d_ = &lds[(KT_) & 1][16384 + (KS) * 6144];                \
    gload_lds16(bSrc[0] + (KT_) * 64 + (KS) * 32, d_ + bOffL[0]);             \
    if (t < 256)                                                              \
      gload_lds16(bSrc[1] + (KT_) * 64 + (KS) * 32, d_ + bOffL[1]); }

  // ---- ds_read swizzled offsets (halfwords, within a kslot region)
  int aRd[2][4], bRd[3];
#pragma unroll
  for (int ch = 0; ch < 2; ++ch)
#pragma unroll
    for (int i = 0; i < 4; ++i) {
      int R = wr * 128 + ch * 64 + i * 16 + lq;
      int p = R >> 1;
      int s8 = ((((R & 1) << 2) | lg)) ^ (p & 7);
      aRd[ch][i] = p * 64 + s8 * 8;
    }
#pragma unroll
  for (int j = 0; j < 3; ++j) {
    int R = wc * 48 + j * 16 + lq;
    int p = R >> 1;
    int s8 = ((((R & 1) << 2) | lg)) ^ (p & 7);
    bRd[j] = p * 64 + s8 * 8;
  }

  f32x4 acc[8][3] = {};

#define PHASE(KT_, KS, CH, STAGE_STMT, VM_STMT)                               \
  { const unsigned short* buf_ = &lds[(KT_) & 1][0];                          \
    bf16x8 af[4], bfv[3];                                                     \
    _Pragma("unroll")                                                         \
    for (int i_ = 0; i_ < 4; ++i_)                                            \
      af[i_] = *reinterpret_cast<const bf16x8*>(buf_ + (KS) * 8192 + aRd[CH][i_]); \
    _Pragma("unroll")                                                         \
    for (int j_ = 0; j_ < 3; ++j_)                                            \
      bfv[j_] = *reinterpret_cast<const bf16x8*>(buf_ + 16384 + (KS) * 6144 + bRd[j_]); \
    STAGE_STMT;                                                               \
    __builtin_amdgcn_s_barrier();                                             \
    __builtin_amdgcn_s_setprio(1);                                            \
    _Pragma("unroll")                                                         \
    for (int i_ = 0; i_ < 4; ++i_)                                            \
      _Pragma("unroll")                                                       \
      for (int j_ = 0; j_ < 3; ++j_)                                          \
        acc[(CH) * 4 + i_][j_] = __builtin_amdgcn_mfma_f32_16x16x32_bf16(     \
            af[i_], bfv[j_], acc[(CH) * 4 + i_][j_], 0, 0, 0);                \
    __builtin_amdgcn_s_setprio(0);                                            \
    VM_STMT;                                                                  \
    __builtin_amdgcn_s_barrier(); }

  // ---- prologue: A/B(0,k0), A/B(0,k1), A/B(1,k0); retire through B(0,k1)
  STAGE_A(0, 0) STAGE_B(0, 0) STAGE_A(0, 1) STAGE_B(0, 1) STAGE_A(1, 0) STAGE_B(1, 0)
  asm volatile("s_waitcnt vmcnt(3)" ::: "memory");
  __builtin_amdgcn_s_barrier();

  for (int kt = 0; kt < KT; ++kt) {
    PHASE(kt, 0, 0, { if (kt + 1 < KT) STAGE_A(kt + 1, 1) }, {})
    PHASE(kt, 0, 1, { if (kt + 1 < KT) STAGE_B(kt + 1, 1) }, {})
    PHASE(kt, 1, 0, { if (kt + 2 < KT) STAGE_A(kt + 2, 0) }, {})
    PHASE(kt, 1, 1, { if (kt + 2 < KT) STAGE_B(kt + 2, 0) },
          { if (kt < KT - 2) { asm volatile("s_waitcnt vmcnt(3)" ::: "memory"); }
            else if (kt == KT - 2) { asm volatile("s_waitcnt vmcnt(0)" ::: "memory"); } })
  }
#undef PHASE
#undef STAGE_A
#undef STAGE_B

  // epilogue: C/D layout col = lane&15, row = (lane>>4)*4 + reg  (m89-verified)
#pragma unroll
  for (int f = 0; f < 8; ++f) {
#pragma unroll
    for (int j = 0; j < 3; ++j) {
#pragma unroll
      for (int r = 0; r < 4; ++r) {
        int m = rb * 256 + wr * 128 + f * 16 + lg * 4 + r;
        int n = cb * 192 + wc * 48 + j * 16 + lq;
        float v = acc[f][j][r];
        int which = n >> 10;
        int h = (n >> 6) & 15;
        int d = n & 63;
        int b = m >> 11;
        int tt = m & 2047;
        int bh = b * H_NUM + h;
        if (which == 0) {
          // fold softmax scale AND log2(e) so attention uses exp2 directly
          q_ws[((size_t)bh * T_SEQ + tt) * H_D + d] = f2bf(v * 0.18033688f);
        } else if (which == 1) {
          k_ws[((size_t)bh * T_SEQ + tt) * H_D + d] = f2bf(v);
        } else {
          // V transposed [BH,D,T'] with per-64-tile k-permutation matching
          // the swapped-QK^T in-register P layout (bijective bit shuffle)
          int k0 = tt & 63;
          int tp = (tt & ~63) | ((k0 & 12) << 1) | ((k0 & 48) >> 3) | (k0 & 1) | ((k0 & 2) << 4);
          v_ws[((size_t)bh * H_D + d) * T_SEQ + tp] = f2bf(v);
        }
      }
    }
  }
}

// ---------------------------------------------------------------- GEMM1  out = y * Wp^T
// (unchanged from round 8: 128x128, grid 512, 2-phase verified structure)
__global__ __launch_bounds__(256, 4) void gemm_proj_kernel(
    const unsigned short* __restrict__ A,
    const unsigned short* __restrict__ Bw,
    float* __restrict__ outf) {
  constexpr int KK = 1024;
  constexpr int KT = KK / 64;

  __shared__ unsigned short lds[16384];   // A 16KB | B 16KB

  const int bid = blockIdx.x;             // NWG = 512
  const int logical = (bid & 7) * 64 + (bid >> 3);
  const int rb = logical >> 3, cb = logical & 7;   // 64 x 8

  const int t = threadIdx.x;
  const int w = t >> 6, l = t & 63;
  const int wr = w >> 1, wc = w & 1;
  const int lq = l & 15, lg = l >> 4;

  const size_t a_base = (size_t)(rb * 128) * KK;
  const size_t b_base = (size_t)(cb * 128) * KK;

  int s_row[4], s_gs[4];
#pragma unroll
  for (int i = 0; i < 4; ++i) {
    int c = t + 256 * i;
    s_row[i] = c >> 3;
    s_gs[i] = (c & 7) ^ (s_row[i] & 7);
  }

  f32x4 acc[4][4] = {};

  for (int kt = 0; kt < KT; ++kt) {
    const int ko = kt * 64;
#pragma unroll
    for (int i = 0; i < 4; ++i) {
      unsigned short* la = &lds[(t + 256 * i) * 8];
      gload_lds16(A + a_base + (size_t)s_row[i] * KK + ko + s_gs[i] * 8, la);
      gload_lds16(Bw + b_base + (size_t)s_row[i] * KK + ko + s_gs[i] * 8, la + 8192);
    }
    __syncthreads();

#pragma unroll
    for (int kk = 0; kk < 2; ++kk) {
      const int sg = kk * 4 + lg;
      bf16x8 af[4], bfv[4];
#pragma unroll
      for (int i = 0; i < 4; ++i) {
        int R = wr * 64 + i * 16 + lq;
        af[i] = *reinterpret_cast<const bf16x8*>(&lds[(R * 8 + (sg ^ (R & 7))) * 8]);
      }
#pragma unroll
      for (int j = 0; j < 4; ++j) {
        int R = wc * 64 + j * 16 + lq;
        bfv[j] = *reinterpret_cast<const bf16x8*>(&lds[8192 + (R * 8 + (sg ^ (R & 7))) * 8]);
      }
#pragma unroll
      for (int i = 0; i < 4; ++i)
#pragma unroll
        for (int j = 0; j < 4; ++j)
          acc[i][j] = __builtin_amdgcn_mfma_f32_16x16x32_bf16(af[i], bfv[j], acc[i][j], 0, 0, 0);
    }
    __syncthreads();
  }

#pragma unroll
  for (int i = 0; i < 4; ++i)
#pragma unroll
    for (int j = 0; j < 4; ++j)
#pragma unroll
      for (int r = 0; r < 4; ++r) {
        int m = rb * 128 + wr * 64 + i * 16 + lg * 4 + r;
        int n = cb * 128 + wc * 64 + j * 16 + lq;
        outf[(size_t)m * 1024 + n] = acc[i][j][r];
      }
}

// ---------------------------------------------------------------- flash attention
// (unchanged -- counted-vmcnt 3-buffer pipeline, swapped QK^T in-lane softmax)
__global__ __launch_bounds__(256, 2) void attn_kernel(
    const unsigned short* __restrict__ qw,
    const unsigned short* __restrict__ kw,
    const unsigned short* __restrict__ vtw,
    unsigned short* __restrict__ yw) {
  __shared__ unsigned short kv_lds[3][8192];   // 3 bufs x (K 4096 | V 4096 shorts) = 48KB

  const int bid = blockIdx.x;
  const int bh = (bid & 7) * 8 + ((bid >> 3) & 7);
  const int qblk = bid >> 6;                    // 0..7, 256 rows each

  const int t = threadIdx.x;
  const int w = t >> 6, l = t & 63;
  const int lq = l & 15, lg = l >> 4;
  const int qbase = qblk * 256 + w * 64;
  const size_t head_off = (size_t)bh * T_SEQ * H_D;

  bf16x8 aq[4][2];
#pragma unroll
  for (int qg = 0; qg < 4; ++qg)
#pragma unroll
    for (int kk = 0; kk < 2; ++kk)
      aq[qg][kk] = *reinterpret_cast<const bf16x8*>(
          qw + head_off + (size_t)(qbase + qg * 16 + lq) * H_D + kk * 32 + lg * 8);

  const unsigned short* sbase[4];
  int sstep[4];
#pragma unroll
  for (int i = 0; i < 4; ++i) {
    int c = w * 64 + l + 256 * i;
    if (c < 512) {
      int row = c >> 3, sl = (c & 7) ^ (row & 7);
      sbase[i] = kw + head_off + row * H_D + sl * 8;
      sstep[i] = 64 * H_D;
    } else {
      int c2 = c - 512;
      int row = c2 >> 3, sl = (c2 & 7) ^ (row & 7);
      sbase[i] = vtw + head_off + (size_t)row * T_SEQ + sl * 8;
      sstep[i] = 64;
    }
  }

  unsigned short* bA = &kv_lds[0][0];
  unsigned short* bB = &kv_lds[1][0];
  unsigned short* bC = &kv_lds[2][0];

#define STAGE(KV, DST)                                                              \
  { _Pragma("unroll")                                                               \
    for (int i = 0; i < 4; ++i)                                                     \
      gload_lds16(sbase[i] + (size_t)(KV) * sstep[i], (DST) + (w * 64 + 256 * i) * 8); }

  STAGE(0, bA)
  STAGE(1, bB)

  f32x4 y[4][4] = {};
  float lrow[4] = {0.f, 0.f, 0.f, 0.f};
  union pa_t { bf16x8 v; unsigned int u[4]; };

  for (int kv = 0; kv < T_SEQ / 64; ++kv) {
    if (kv == T_SEQ / 64 - 1) {
      asm volatile("s_waitcnt vmcnt(0)" ::: "memory");
    } else {
      asm volatile("s_waitcnt vmcnt(4)" ::: "memory");
    }
    __builtin_amdgcn_s_barrier();

    bf16x8 kf[8], vf[8];
#pragma unroll
    for (int f = 0; f < 8; ++f) {
      int row = (f >> 1) * 16 + lq;
      int sl = ((f & 1) * 4 + lg) ^ (lq & 7);
      kf[f] = *reinterpret_cast<const bf16x8*>(bA + row * 64 + sl * 8);
    }
#pragma unroll
    for (int db = 0; db < 4; ++db)
#pragma unroll
      for (int ks = 0; ks < 2; ++ks) {
        int row = db * 16 + lq;
        int sl = (ks * 4 + lg) ^ (lq & 7);
        vf[db * 2 + ks] = *reinterpret_cast<const bf16x8*>(bA + 4096 + row * 64 + sl * 8);
      }

    pa_t pa0[4], pa1[4];
#pragma unroll
    for (int qg = 0; qg < 4; ++qg) {
      f32x4 s[4];
#pragma unroll
      for (int tt = 0; tt < 4; ++tt) {
        f32x4 z = {0.f, 0.f, 0.f, 0.f};
        s[tt] = __builtin_amdgcn_mfma_f32_16x16x32_bf16(kf[tt * 2], aq[qg][0], z, 0, 0, 0);
        s[tt] = __builtin_amdgcn_mfma_f32_16x16x32_bf16(kf[tt * 2 + 1], aq[qg][1], s[tt], 0, 0, 0);
      }
      float acc_e = 0.f;
#pragma unroll
      for (int tt = 0; tt < 4; ++tt) {
        float e0 = __builtin_amdgcn_exp2f(s[tt][0]);
        float e1 = __builtin_amdgcn_exp2f(s[tt][1]);
        float e2 = __builtin_amdgcn_exp2f(s[tt][2]);
        float e3 = __builtin_amdgcn_exp2f(s[tt][3]);
        pa0[qg].u[tt] = pack_hi(e0, e1);
        pa1[qg].u[tt] = pack_hi(e2, e3);
        acc_e += (e0 + e1) + (e2 + e3);
      }
      lrow[qg] += acc_e;
    }

#pragma unroll
    for (int qg = 0; qg < 4; ++qg)
#pragma unroll
      for (int db = 0; db < 4; ++db) {
        y[qg][db] = __builtin_amdgcn_mfma_f32_16x16x32_bf16(pa0[qg].v, vf[db * 2], y[qg][db], 0, 0, 0);
        y[qg][db] = __builtin_amdgcn_mfma_f32_16x16x32_bf16(pa1[qg].v, vf[db * 2 + 1], y[qg][db], 0, 0, 0);
      }

    if (kv + 2 < T_SEQ / 64) STAGE(kv + 2, bC)

    unsigned short* tmp = bA; bA = bB; bB = bC; bC = tmp;
  }
#undef STAGE

  const int b = bh >> 4, h = bh & 15;
#pragma unroll
  for (int qg = 0; qg < 4; ++qg) {
    float sm = lrow[qg];
    sm += __shfl_xor(sm, 16);
    sm += __shfl_xor(sm, 32);
    float inv = 1.0f / sm;
#pragma unroll
    for (int r = 0; r < 4; ++r) {
      float iv = __shfl(inv, lg * 4 + r);
      int row = qbase + qg * 16 + lg * 4 + r;
#pragma unroll
      for (int db = 0; db < 4; ++db) {
        int d = db * 16 + lq;
        yw[((size_t)(b * T_SEQ + row)) * C_DIM + h * 64 + d] = f2bf(y[qg][db][r] * iv);
      }
    }
  }
}

// ---------------------------------------------------------------- launch
extern "C" void kernel_launch(void* const* d_in, const int* in_sizes, int n_in,
                              void* d_out, int out_size, void* d_ws, size_t ws_size,
                              hipStream_t stream) {
  (void)in_sizes; (void)n_in; (void)out_size; (void)ws_size;
  const float* x      = (const float*)d_in[0];
  const float* w_attn = (const float*)d_in[1];
  const float* w_proj = (const float*)d_in[2];
  float* out = (float*)d_out;

  unsigned short* ws = (unsigned short*)d_ws;
  const size_t XB = (size_t)M_ROWS * C_DIM;          // 8,388,608
  unsigned short* xb  = ws;                          // x bf16 [8192,1024]; reused as y after attn
  unsigned short* wab = xb + XB;                     // w_attn bf16 [3072,1024]
  unsigned short* wpb = wab + (size_t)3072 * 1024;   // w_proj bf16 [1024,1024]
  unsigned short* qws = wpb + (size_t)1024 * 1024;   // q [BH,T,D] (pre-scaled by 0.125*log2e)
  unsigned short* kws = qws + XB;                    // k [BH,T,D]
  unsigned short* vws = kws + XB;                    // v^T [BH,D,T'] k-permuted
  unsigned short* yws = xb;                          // attention output [B,T,C] (xb dead by then)

  cast_all_kernel<<<3145728 / 256, 256, 0, stream>>>(x, w_attn, w_proj, xb, wab, wpb);

  gemm_qkv8_kernel<<<512, 512, 0, stream>>>(xb, wab, qws, kws, vws);
  attn_kernel<<<512, 256, 0, stream>>>(qws, kws, vws, yws);
  gemm_proj_kernel<<<512, 256, 0, stream>>>(yws, wpb, out);
}

// Round 10
// 187.009 us; speedup vs baseline: 1.0130x; 1.0130x over previous
//
#include <hip/hip_runtime.h>

// Problem constants
#define T_SEQ 2048
#define C_DIM 1024
#define H_NUM 16
#define H_D   64
#define B_NUM 4
#define M_ROWS 8192   // B*T

typedef __attribute__((ext_vector_type(4))) float f32x4;
typedef __attribute__((ext_vector_type(8))) short bf16x8;   // 8 bf16 = 4 VGPRs

__device__ __forceinline__ unsigned short f2bf(float f) {
  union { float f; unsigned int u; } a;
  a.f = f;
  unsigned int u = a.u;
  u += 0x7fffu + ((u >> 16) & 1u);   // RNE
  return (unsigned short)(u >> 16);
}

__device__ __forceinline__ unsigned int fbits(float f) {
  union { float f; unsigned int u; } a; a.f = f; return a.u;
}

// pack the high halves (bf16-truncate) of two f32 into one u32: {hi(b), hi(a)}
__device__ __forceinline__ unsigned int pack_hi(float a, float b) {
#if __has_builtin(__builtin_amdgcn_perm)
  return __builtin_amdgcn_perm(fbits(b), fbits(a), 0x07060302u);  // 1 VALU op
#else
  return (fbits(b) & 0xffff0000u) | (fbits(a) >> 16);
#endif
}

// async global->LDS, 16B per lane; LDS dest = wave-uniform base + lane*16
__device__ __forceinline__ void gload_lds16(const unsigned short* g, unsigned short* l) {
  __builtin_amdgcn_global_load_lds(
      (const __attribute__((address_space(1))) unsigned int*)g,
      (__attribute__((address_space(3))) unsigned int*)l, 16, 0, 0);
}

// ---------------------------------------------------------------- fused cast fp32 -> bf16
__global__ __launch_bounds__(256) void cast_all_kernel(const float* __restrict__ x,
                                                       const float* __restrict__ wa,
                                                       const float* __restrict__ wp,
                                                       unsigned short* __restrict__ xb,
                                                       unsigned short* __restrict__ wab,
                                                       unsigned short* __restrict__ wpb) {
  int i = blockIdx.x * 256 + threadIdx.x;
  const float* src;
  unsigned short* dst;
  int off;
  if (i < 2097152) {           // x: 8192*1024/4
    src = x; dst = xb; off = i;
  } else if (i < 2883584) {    // w_attn: 3072*1024/4
    src = wa; dst = wab; off = i - 2097152;
  } else {                     // w_proj: 1024*1024/4
    src = wp; dst = wpb; off = i - 2883584;
  }
  float4 v = reinterpret_cast<const float4*>(src)[off];
  ushort4 o;
  o.x = f2bf(v.x); o.y = f2bf(v.y); o.z = f2bf(v.z); o.w = f2bf(v.w);
  reinterpret_cast<ushort4*>(dst)[off] = o;
}

// ---------------------------------------------------------------- GEMM0 (QKV) -- 8-phase, take 3
// Round 10: r9's failure isolated to ONE protocol violation: the B-stage's
// `if (t<256)` guard made per-wave load counts non-uniform (8 vs 6 per
// K-tile) -> vmcnt, a per-wave FIFO counter, retired DIFFERENT logical
// stages on different waves -> counted-wait discipline corrupted (occupancy
// 19.5% < 25% cap = waves idling at waits). r2's separate defect: 1-2 phase
// issue->use lead (drain-equivalent). This version closes every defect:
//  * BN=192 -> grid 32x16 = 512 = 2 EXACT rounds at 1 blk/CU (no tail).
//  * UNIFORM stages: A k-split regions (256 rows x 32hw, 2 loads/thread),
//    B whole-K region (192 rows x 64hw, exactly 3 loads/thread).
//  * Stage plan p0->B(kt+1), p1->Ak0(kt+1), p2->Ak1(kt+1): 4-6 barrier
//    issue->use leads. FIFO-proven waits: vmcnt(5) @p1-end (retires exactly
//    Ak1(kt)), vmcnt(2) @p3-end (retires B+Ak0(kt+1), leaves Ak1(kt+1)).
//    Never drains until kt=KT-1.
//  * bfv read once per kk, reused across both mq phases.
//  * explicit lgkmcnt(0) after each barrier; setprio(1) around MFMA (T5).
//  * Swizzles verbatim from HW-verified kernels (0 conflicts): A = r9's
//    2-rows-per-128B scheme, B = r0-r8's 8-slot scheme; linear LDS dest +
//    pre-swizzled global source (rule #21).
// Regions per buf (halfwords): Ak0@0 (8192) | Ak1@8192 (8192) | B@16384 (12288).
// LDS 2 x 57344B = 114688 (ran on HW in r2/r9). acc[8][3]=96 + temps < 256 @ (512,2).
__global__ __launch_bounds__(512, 2) void gemm_qkv8_kernel(
    const unsigned short* __restrict__ A,
    const unsigned short* __restrict__ Bw,
    unsigned short* __restrict__ q_ws,
    unsigned short* __restrict__ k_ws,
    unsigned short* __restrict__ v_ws) {
  constexpr int KK = 1024;
  constexpr int KT = KK / 64;            // 16 K-tiles

  __shared__ __align__(16) unsigned short lds[2][28672];   // 112KB

  const int bid = blockIdx.x;            // NWG = 512, %8 == 0
  const int logical = (bid & 7) * 64 + (bid >> 3);
  const int rb = logical >> 4, cb = logical & 15;   // 32 x 16

  const int t = threadIdx.x;
  const int w = t >> 6, l = t & 63;
  const int wr = w >> 2, wc = w & 3;     // 2M x 4N wave grid
  const int lq = l & 15, lg = l >> 4;

  const size_t a_base = (size_t)(rb * 256) * KK;
  const size_t b_base = (size_t)(cb * 192) * KK;

  // ---- A staging (per kslot region: 1024 chunks, 2/thread, UNIFORM)
  // chunk c -> LDS phys (p=c>>3, slot8=c&7); sp=(c&7)^(p&7);
  // row r=(p<<1)|(sp>>2), k16=sp&3.
  const unsigned short* aSrc[2];
  int aOffL[2];
#pragma unroll
  for (int i = 0; i < 2; ++i) {
    int c = t + 512 * i;
    int p = c >> 3, sp = (c & 7) ^ (p & 7);
    int r = (p << 1) | (sp >> 2);
    aSrc[i] = A + a_base + (size_t)r * KK + (sp & 3) * 8;
    aOffL[i] = c * 8;
  }
  // ---- B staging (whole-K region: 1536 chunks, 3/thread, UNIFORM)
  // chunk c -> LDS (row r=c>>3, slot8=c&7); global k-slot s=(c&7)^(r&7).
  const unsigned short* bSrc[3];
  int bOffL[3];
#pragma unroll
  for (int i = 0; i < 3; ++i) {
    int c = t + 512 * i;
    int r = c >> 3, s = (c & 7) ^ (r & 7);
    bSrc[i] = Bw + b_base + (size_t)r * KK + s * 8;
    bOffL[i] = c * 8;
  }

#define STAGE_A(KT_, KS)                                                      \
  { unsigned short* d_ = &lds[(KT_) & 1][(KS) * 8192];                        \
    _Pragma("unroll")                                                         \
    for (int i_ = 0; i_ < 2; ++i_)                                            \
      gload_lds16(aSrc[i_] + (KT_) * 64 + (KS) * 32, d_ + aOffL[i_]); }

#define STAGE_B(KT_)                                                          \
  { unsigned short* d_ = &lds[(KT_) & 1][16384];                              \
    _Pragma("unroll")                                                         \
    for (int i_ = 0; i_ < 3; ++i_)                                            \
      gload_lds16(bSrc[i_] + (KT_) * 64, d_ + bOffL[i_]); }

  // ---- ds_read offsets
  // A (within a kslot region): R = wr*128 + mq*64 + i*16 + lq, k16 = lg:
  //   p = R>>1, slot8 = (((R&1)<<2)|lg) ^ (p&7)  [2-way free, r9-verified]
  int aRd[2][4];
#pragma unroll
  for (int mq = 0; mq < 2; ++mq)
#pragma unroll
    for (int i = 0; i < 4; ++i) {
      int R = wr * 128 + mq * 64 + i * 16 + lq;
      int p = R >> 1;
      int s8 = ((((R & 1) << 2) | lg)) ^ (p & 7);
      aRd[mq][i] = p * 64 + s8 * 8;
    }
  // B (whole-K region): R = wc*48 + j*16 + lq, sg = kk*4+lg:
  //   off = R*64 + (sg^(R&7))*8   [r0-r8 verified, 0 conflicts]
  int bRd[2][3];
#pragma unroll
  for (int kk = 0; kk < 2; ++kk)
#pragma unroll
    for (int j = 0; j < 3; ++j) {
      int R = wc * 48 + j * 16 + lq;
      int sg = kk * 4 + lg;
      bRd[kk][j] = R * 64 + (sg ^ (R & 7)) * 8;
    }

  f32x4 acc[8][3] = {};
  bf16x8 bfv[3];

#define MM(MQ)                                                                \
  { _Pragma("unroll")                                                         \
    for (int i_ = 0; i_ < 4; ++i_)                                            \
      _Pragma("unroll")                                                       \
      for (int j_ = 0; j_ < 3; ++j_)                                          \
        acc[(MQ) * 4 + i_][j_] = __builtin_amdgcn_mfma_f32_16x16x32_bf16(     \
            af[i_], bfv[j_], acc[(MQ) * 4 + i_][j_], 0, 0, 0); }

#define BAR()  __builtin_amdgcn_s_barrier()
#define LG0()  asm volatile("s_waitcnt lgkmcnt(0)" ::: "memory")

  // ---- prologue: B(0), Ak0(0), Ak1(0) -> buf0 (7 loads);
  // need B(0)+Ak0(0) for p0 -> vmcnt(2) leaves Ak1(0) in flight.
  STAGE_B(0) STAGE_A(0, 0) STAGE_A(0, 1)
  asm volatile("s_waitcnt vmcnt(2)" ::: "memory");
  BAR();

  for (int kt = 0; kt < KT; ++kt) {
    const unsigned short* buf = &lds[kt & 1][0];
    // ---- p0: (mq0, kk0); read Ak0+B(kk0); stage B(kt+1)
    {
      bf16x8 af[4];
#pragma unroll
      for (int i = 0; i < 4; ++i)
        af[i] = *reinterpret_cast<const bf16x8*>(buf + aRd[0][i]);
#pragma unroll
      for (int j = 0; j < 3; ++j)
        bfv[j] = *reinterpret_cast<const bf16x8*>(buf + 16384 + bRd[0][j]);
      if (kt + 1 < KT) STAGE_B(kt + 1)
      BAR(); LG0();
      __builtin_amdgcn_s_setprio(1);
      MM(0)
      __builtin_amdgcn_s_setprio(0);
      BAR();
    }
    // ---- p1: (mq1, kk0) reusing bfv; stage Ak0(kt+1); wait retires Ak1(kt)
    {
      bf16x8 af[4];
#pragma unroll
      for (int i = 0; i < 4; ++i)
        af[i] = *reinterpret_cast<const bf16x8*>(buf + aRd[1][i]);
      if (kt + 1 < KT) STAGE_A(kt + 1, 0)
      BAR(); LG0();
      __builtin_amdgcn_s_setprio(1);
      MM(1)
      __builtin_amdgcn_s_setprio(0);
      if (kt < KT - 1) { asm volatile("s_waitcnt vmcnt(5)" ::: "memory"); }
      else            { asm volatile("s_waitcnt vmcnt(0)" ::: "memory"); }
      BAR();
    }
    // ---- p2: (mq0, kk1); read Ak1+B(kk1); stage Ak1(kt+1)
    {
      bf16x8 af[4];
#pragma unroll
      for (int i = 0; i < 4; ++i)
        af[i] = *reinterpret_cast<const bf16x8*>(buf + 8192 + aRd[0][i]);
#pragma unroll
      for (int j = 0; j < 3; ++j)
        bfv[j] = *reinterpret_cast<const bf16x8*>(buf + 16384 + bRd[1][j]);
      if (kt + 1 < KT) STAGE_A(kt + 1, 1)
      BAR(); LG0();
      __builtin_amdgcn_s_setprio(1);
      MM(0)
      __builtin_amdgcn_s_setprio(0);
      BAR();
    }
    // ---- p3: (mq1, kk1) reusing bfv; wait retires B(kt+1)+Ak0(kt+1)
    {
      bf16x8 af[4];
#pragma unroll
      for (int i = 0; i < 4; ++i)
        af[i] = *reinterpret_cast<const bf16x8*>(buf + 8192 + aRd[1][i]);
      BAR(); LG0();
      __builtin_amdgcn_s_setprio(1);
      MM(1)
      __builtin_amdgcn_s_setprio(0);
      if (kt < KT - 1) { asm volatile("s_waitcnt vmcnt(2)" ::: "memory"); }
      BAR();
    }
  }
#undef MM
#undef BAR
#undef LG0
#undef STAGE_A
#undef STAGE_B

  // epilogue: C/D layout col = lane&15, row = (lane>>4)*4 + reg  (m89-verified;
  // this exact BN=192 indexing refcheck-passed in r9)
#pragma unroll
  for (int f = 0; f < 8; ++f) {
#pragma unroll
    for (int j = 0; j < 3; ++j) {
#pragma unroll
      for (int r = 0; r < 4; ++r) {
        int m = rb * 256 + wr * 128 + f * 16 + lg * 4 + r;
        int n = cb * 192 + wc * 48 + j * 16 + lq;
        float v = acc[f][j][r];
        int which = n >> 10;
        int h = (n >> 6) & 15;
        int d = n & 63;
        int b = m >> 11;
        int tt = m & 2047;
        int bh = b * H_NUM + h;
        if (which == 0) {
          // fold softmax scale AND log2(e) so attention uses exp2 directly
          q_ws[((size_t)bh * T_SEQ + tt) * H_D + d] = f2bf(v * 0.18033688f);
        } else if (which == 1) {
          k_ws[((size_t)bh * T_SEQ + tt) * H_D + d] = f2bf(v);
        } else {
          // V transposed [BH,D,T'] with per-64-tile k-permutation matching
          // the swapped-QK^T in-register P layout (bijective bit shuffle)
          int k0 = tt & 63;
          int tp = (tt & ~63) | ((k0 & 12) << 1) | ((k0 & 48) >> 3) | (k0 & 1) | ((k0 & 2) << 4);
          v_ws[((size_t)bh * H_D + d) * T_SEQ + tp] = f2bf(v);
        }
      }
    }
  }
}

// ---------------------------------------------------------------- GEMM1  out = y * Wp^T
// (round-8 measured-best: 128x128, grid 512, 2-phase verified structure)
__global__ __launch_bounds__(256, 4) void gemm_proj_kernel(
    const unsigned short* __restrict__ A,
    const unsigned short* __restrict__ Bw,
    float* __restrict__ outf) {
  constexpr int KK = 1024;
  constexpr int KT = KK / 64;

  __shared__ unsigned short lds[16384];   // A 16KB | B 16KB

  const int bid = blockIdx.x;             // NWG = 512
  const int logical = (bid & 7) * 64 + (bid >> 3);
  const int rb = logical >> 3, cb = logical & 7;   // 64 x 8

  const int t = threadIdx.x;
  const int w = t >> 6, l = t & 63;
  const int wr = w >> 1, wc = w & 1;
  const int lq = l & 15, lg = l >> 4;

  const size_t a_base = (size_t)(rb * 128) * KK;
  const size_t b_base = (size_t)(cb * 128) * KK;

  int s_row[4], s_gs[4];
#pragma unroll
  for (int i = 0; i < 4; ++i) {
    int c = t + 256 * i;
    s_row[i] = c >> 3;
    s_gs[i] = (c & 7) ^ (s_row[i] & 7);
  }

  f32x4 acc[4][4] = {};

  for (int kt = 0; kt < KT; ++kt) {
    const int ko = kt * 64;
#pragma unroll
    for (int i = 0; i < 4; ++i) {
      unsigned short* la = &lds[(t + 256 * i) * 8];
      gload_lds16(A + a_base + (size_t)s_row[i] * KK + ko + s_gs[i] * 8, la);
      gload_lds16(Bw + b_base + (size_t)s_row[i] * KK + ko + s_gs[i] * 8, la + 8192);
    }
    __syncthreads();

#pragma unroll
    for (int kk = 0; kk < 2; ++kk) {
      const int sg = kk * 4 + lg;
      bf16x8 af[4], bfv[4];
#pragma unroll
      for (int i = 0; i < 4; ++i) {
        int R = wr * 64 + i * 16 + lq;
        af[i] = *reinterpret_cast<const bf16x8*>(&lds[(R * 8 + (sg ^ (R & 7))) * 8]);
      }
#pragma unroll
      for (int j = 0; j < 4; ++j) {
        int R = wc * 64 + j * 16 + lq;
        bfv[j] = *reinterpret_cast<const bf16x8*>(&lds[8192 + (R * 8 + (sg ^ (R & 7))) * 8]);
      }
#pragma unroll
      for (int i = 0; i < 4; ++i)
#pragma unroll
        for (int j = 0; j < 4; ++j)
          acc[i][j] = __builtin_amdgcn_mfma_f32_16x16x32_bf16(af[i], bfv[j], acc[i][j], 0, 0, 0);
    }
    __syncthreads();
  }

#pragma unroll
  for (int i = 0; i < 4; ++i)
#pragma unroll
    for (int j = 0; j < 4; ++j)
#pragma unroll
      for (int r = 0; r < 4; ++r) {
        int m = rb * 128 + wr * 64 + i * 16 + lg * 4 + r;
        int n = cb * 128 + wc * 64 + j * 16 + lq;
        outf[(size_t)m * 1024 + n] = acc[i][j][r];
      }
}

// ---------------------------------------------------------------- flash attention
// (unchanged -- counted-vmcnt 3-buffer pipeline, swapped QK^T in-lane softmax)
__global__ __launch_bounds__(256, 2) void attn_kernel(
    const unsigned short* __restrict__ qw,
    const unsigned short* __restrict__ kw,
    const unsigned short* __restrict__ vtw,
    unsigned short* __restrict__ yw) {
  __shared__ unsigned short kv_lds[3][8192];   // 3 bufs x (K 4096 | V 4096 shorts) = 48KB

  const int bid = blockIdx.x;
  const int bh = (bid & 7) * 8 + ((bid >> 3) & 7);
  const int qblk = bid >> 6;                    // 0..7, 256 rows each

  const int t = threadIdx.x;
  const int w = t >> 6, l = t & 63;
  const int lq = l & 15, lg = l >> 4;
  const int qbase = qblk * 256 + w * 64;
  const size_t head_off = (size_t)bh * T_SEQ * H_D;

  bf16x8 aq[4][2];
#pragma unroll
  for (int qg = 0; qg < 4; ++qg)
#pragma unroll
    for (int kk = 0; kk < 2; ++kk)
      aq[qg][kk] = *reinterpret_cast<const bf16x8*>(
          qw + head_off + (size_t)(qbase + qg * 16 + lq) * H_D + kk * 32 + lg * 8);

  const unsigned short* sbase[4];
  int sstep[4];
#pragma unroll
  for (int i = 0; i < 4; ++i) {
    int c = w * 64 + l + 256 * i;
    if (c < 512) {
      int row = c >> 3, sl = (c & 7) ^ (row & 7);
      sbase[i] = kw + head_off + row * H_D + sl * 8;
      sstep[i] = 64 * H_D;
    } else {
      int c2 = c - 512;
      int row = c2 >> 3, sl = (c2 & 7) ^ (row & 7);
      sbase[i] = vtw + head_off + (size_t)row * T_SEQ + sl * 8;
      sstep[i] = 64;
    }
  }

  unsigned short* bA = &kv_lds[0][0];
  unsigned short* bB = &kv_lds[1][0];
  unsigned short* bC = &kv_lds[2][0];

#define STAGE(KV, DST)                                                              \
  { _Pragma("unroll")                                                               \
    for (int i = 0; i < 4; ++i)                                                     \
      gload_lds16(sbase[i] + (size_t)(KV) * sstep[i], (DST) + (w * 64 + 256 * i) * 8); }

  STAGE(0, bA)
  STAGE(1, bB)

  f32x4 y[4][4] = {};
  float lrow[4] = {0.f, 0.f, 0.f, 0.f};
  union pa_t { bf16x8 v; unsigned int u[4]; };

  for (int kv = 0; kv < T_SEQ / 64; ++kv) {
    if (kv == T_SEQ / 64 - 1) {
      asm volatile("s_waitcnt vmcnt(0)" ::: "memory");
    } else {
      asm volatile("s_waitcnt vmcnt(4)" ::: "memory");
    }
    __builtin_amdgcn_s_barrier();

    bf16x8 kf[8], vf[8];
#pragma unroll
    for (int f = 0; f < 8; ++f) {
      int row = (f >> 1) * 16 + lq;
      int sl = ((f & 1) * 4 + lg) ^ (lq & 7);
      kf[f] = *reinterpret_cast<const bf16x8*>(bA + row * 64 + sl * 8);
    }
#pragma unroll
    for (int db = 0; db < 4; ++db)
#pragma unroll
      for (int ks = 0; ks < 2; ++ks) {
        int row = db * 16 + lq;
        int sl = (ks * 4 + lg) ^ (lq & 7);
        vf[db * 2 + ks] = *reinterpret_cast<const bf16x8*>(bA + 4096 + row * 64 + sl * 8);
      }

    pa_t pa0[4], pa1[4];
#pragma unroll
    for (int qg = 0; qg < 4; ++qg) {
      f32x4 s[4];
#pragma unroll
      for (int tt = 0; tt < 4; ++tt) {
        f32x4 z = {0.f, 0.f, 0.f, 0.f};
        s[tt] = __builtin_amdgcn_mfma_f32_16x16x32_bf16(kf[tt * 2], aq[qg][0], z, 0, 0, 0);
        s[tt] = __builtin_amdgcn_mfma_f32_16x16x32_bf16(kf[tt * 2 + 1], aq[qg][1], s[tt], 0, 0, 0);
      }
      float acc_e = 0.f;
#pragma unroll
      for (int tt = 0; tt < 4; ++tt) {
        float e0 = __builtin_amdgcn_exp2f(s[tt][0]);
        float e1 = __builtin_amdgcn_exp2f(s[tt][1]);
        float e2 = __builtin_amdgcn_exp2f(s[tt][2]);
        float e3 = __builtin_amdgcn_exp2f(s[tt][3]);
        pa0[qg].u[tt] = pack_hi(e0, e1);
        pa1[qg].u[tt] = pack_hi(e2, e3);
        acc_e += (e0 + e1) + (e2 + e3);
      }
      lrow[qg] += acc_e;
    }

#pragma unroll
    for (int qg = 0; qg < 4; ++qg)
#pragma unroll
      for (int db = 0; db < 4; ++db) {
        y[qg][db] = __builtin_amdgcn_mfma_f32_16x16x32_bf16(pa0[qg].v, vf[db * 2], y[qg][db], 0, 0, 0);
        y[qg][db] = __builtin_amdgcn_mfma_f32_16x16x32_bf16(pa1[qg].v, vf[db * 2 + 1], y[qg][db], 0, 0, 0);
      }

    if (kv + 2 < T_SEQ / 64) STAGE(kv + 2, bC)

    unsigned short* tmp = bA; bA = bB; bB = bC; bC = tmp;
  }
#undef STAGE

  const int b = bh >> 4, h = bh & 15;
#pragma unroll
  for (int qg = 0; qg < 4; ++qg) {
    float sm = lrow[qg];
    sm += __shfl_xor(sm, 16);
    sm += __shfl_xor(sm, 32);
    float inv = 1.0f / sm;
#pragma unroll
    for (int r = 0; r < 4; ++r) {
      float iv = __shfl(inv, lg * 4 + r);
      int row = qbase + qg * 16 + lg * 4 + r;
#pragma unroll
      for (int db = 0; db < 4; ++db) {
        int d = db * 16 + lq;
        yw[((size_t)(b * T_SEQ + row)) * C_DIM + h * 64 + d] = f2bf(y[qg][db][r] * iv);
      }
    }
  }
}

// ---------------------------------------------------------------- launch
extern "C" void kernel_launch(void* const* d_in, const int* in_sizes, int n_in,
                              void* d_out, int out_size, void* d_ws, size_t ws_size,
                              hipStream_t stream) {
  (void)in_sizes; (void)n_in; (void)out_size; (void)ws_size;
  const float* x      = (const float*)d_in[0];
  const float* w_attn = (const float*)d_in[1];
  const float* w_proj = (const float*)d_in[2];
  float* out = (float*)d_out;

  unsigned short* ws = (unsigned short*)d_ws;
  const size_t XB = (size_t)M_ROWS * C_DIM;          // 8,388,608
  unsigned short* xb  = ws;                          // x bf16 [8192,1024]; reused as y after attn
  unsigned short* wab = xb + XB;                     // w_attn bf16 [3072,1024]
  unsigned short* wpb = wab + (size_t)3072 * 1024;   // w_proj bf16 [1024,1024]
  unsigned short* qws = wpb + (size_t)1024 * 1024;   // q [BH,T,D] (pre-scaled by 0.125*log2e)
  unsigned short* kws = qws + XB;                    // k [BH,T,D]
  unsigned short* vws = kws + XB;                    // v^T [BH,D,T'] k-permuted
  unsigned short* yws = xb;                          // attention output [B,T,C] (xb dead by then)

  cast_all_kernel<<<3145728 / 256, 256, 0, stream>>>(x, w_attn, w_proj, xb, wab, wpb);

  gemm_qkv8_kernel<<<512, 512, 0, stream>>>(xb, wab, qws, kws, vws);
  attn_kernel<<<512, 256, 0, stream>>>(qws, kws, vws, yws);
  gemm_proj_kernel<<<512, 256, 0, stream>>>(yws, wpb, out);
}

// Round 11
// 177.070 us; speedup vs baseline: 1.0698x; 1.0561x over previous
//
#include <hip/hip_runtime.h>

// Problem constants
#define T_SEQ 2048
#define C_DIM 1024
#define H_NUM 16
#define H_D   64
#define B_NUM 4
#define M_ROWS 8192   // B*T

typedef __attribute__((ext_vector_type(4))) float f32x4;
typedef __attribute__((ext_vector_type(8))) short bf16x8;   // 8 bf16 = 4 VGPRs (per guide §3)

__device__ __forceinline__ unsigned short f2bf(float f) {
  union { float f; unsigned int u; } a;
  a.f = f;
  unsigned int u = a.u;
  u += 0x7fffu + ((u >> 16) & 1u);   // RNE
  return (unsigned short)(u >> 16);
}

__device__ __forceinline__ unsigned int fbits(float f) {
  union { float f; unsigned int u; } a; a.f = f; return a.u;
}

// pack the high halves (bf16-truncate) of two f32 into one u32: {hi(b), hi(a)}
__device__ __forceinline__ unsigned int pack_hi(float a, float b) {
#if __has_builtin(__builtin_amdgcn_perm)
  return __builtin_amdgcn_perm(fbits(b), fbits(a), 0x07060302u);  // 1 VALU op
#else
  return (fbits(b) & 0xffff0000u) | (fbits(a) >> 16);
#endif
}

// async global->LDS, 16B per lane; LDS dest = wave-uniform base + lane*16
__device__ __forceinline__ void gload_lds16(const unsigned short* g, unsigned short* l) {
  __builtin_amdgcn_global_load_lds(
      (const __attribute__((address_space(1))) unsigned int*)g,
      (__attribute__((address_space(3))) unsigned int*)l, 16, 0, 0);
}

// ---------------------------------------------------------------- fused cast fp32 -> bf16
__global__ __launch_bounds__(256) void cast_all_kernel(const float* __restrict__ x,
                                                       const float* __restrict__ wa,
                                                       const float* __restrict__ wp,
                                                       unsigned short* __restrict__ xb,
                                                       unsigned short* __restrict__ wab,
                                                       unsigned short* __restrict__ wpb) {
  int i = blockIdx.x * 256 + threadIdx.x;
  const float* src;
  unsigned short* dst;
  int off;
  if (i < 2097152) {           // x: 8192*1024/4
    src = x; dst = xb; off = i;
  } else if (i < 2883584) {    // w_attn: 3072*1024/4
    src = wa; dst = wab; off = i - 2097152;
  } else {                     // w_proj: 1024*1024/4
    src = wp; dst = wpb; off = i - 2883584;
  }
  float4 v = reinterpret_cast<const float4*>(src)[off];
  ushort4 o;
  o.x = f2bf(v.x); o.y = f2bf(v.y); o.z = f2bf(v.z); o.w = f2bf(v.w);
  reinterpret_cast<ushort4*>(dst)[off] = o;
}

// ---------------------------------------------------------------- GEMM  C = A * B^T
// FINAL (round 11 = round 8 verbatim, the measured session best: 177.47 us).
// Session-closed findings backing this config:
//  * 2-phase law: TF = I x ~4.4 B/cy/block x blk/CU x 0.614, verified on
//    6 configs (r0/r1/r4/r7 + BK variants). 128x96 @ 4 blk/CU with grid
//    64x32 = 2048 = exactly 2 resident rounds is the constrained optimum
//    (acc <= 64 f32/thread under the unified VGPR+AGPR 128-reg cap of
//    (256,4); BM=128 fixed by fragment geometry; grid quantization).
//  * Bigger tiles: r5/r6 spilled (unified-file law); r7 legal test showed
//    rate is per-block -> halving blocks for intensity is net-negative.
//  * 8-phase schedule: 3 defect-closed ports (r2/r9/r10) all null at
//    17-19% MfmaUtil -> closed for this shape in plain HIP.
//  * Aggregate staged rate at optimum ~10.3 TB/s (L3-delivery bound;
//    HBM 18%, L2 under ceiling, conflicts 0).
// EPI 0: QKV epilogue -> q*0.125*log2e, k [BH,T,D], v^T [BH,D,T'] k-permuted
// EPI 1: plain fp32 row-major [M,1024] output
template <int EPI>
__global__ __launch_bounds__(256, 4) void gemm_bt_kernel(
    const unsigned short* __restrict__ A,
    const unsigned short* __restrict__ Bw,
    unsigned short* __restrict__ q_ws,
    unsigned short* __restrict__ k_ws,
    unsigned short* __restrict__ v_ws,
    float* __restrict__ outf) {
  constexpr int BN  = (EPI == 0) ? 96 : 128;
  constexpr int NN  = (EPI == 0) ? 3072 : 1024;
  constexpr int NBC = NN / BN;           // 32 or 8
  constexpr int NFR = BN / 32;           // n-frags per wave: 3 or 4
  constexpr int BLD = BN * 8 / 256;      // B staging chunks per thread: 3 or 4
  constexpr int KK  = 1024;
  constexpr int KT  = KK / 64;           // 16
  constexpr int NWG = 64 * NBC;          // 2048 or 512 (both % 8 == 0)

  __shared__ unsigned short lds[8192 + BN * 64];   // A 16KB | B 12KB/16KB

  // T1: bijective XCD-aware swizzle (NWG % 8 == 0)
  const int bid = blockIdx.x;
  const int logical = (bid & 7) * (NWG / 8) + (bid >> 3);
  const int rb = logical / NBC, cb = logical % NBC;

  const int t = threadIdx.x;
  const int w = t >> 6, l = t & 63;
  const int wr = w >> 1, wc = w & 1;
  const int lq = l & 15, lg = l >> 4;

  const size_t a_base = (size_t)(rb * 128) * KK;
  const size_t b_base = (size_t)(cb * BN) * KK;

  // staging chunk c = t + 256*i -> (row=c>>3, slot=c&7), src slot ^= row&7
  int aRow[4], aGs[4];
#pragma unroll
  for (int i = 0; i < 4; ++i) {
    int c = t + 256 * i;
    aRow[i] = c >> 3;
    aGs[i] = (c & 7) ^ (aRow[i] & 7);
  }
  int bRow[BLD], bGs[BLD];
#pragma unroll
  for (int i = 0; i < BLD; ++i) {
    int c = t + 256 * i;
    bRow[i] = c >> 3;
    bGs[i] = (c & 7) ^ (bRow[i] & 7);
  }

  f32x4 acc[4][NFR] = {};

  for (int kt = 0; kt < KT; ++kt) {
    const int ko = kt * 64;
#pragma unroll
    for (int i = 0; i < 4; ++i)
      gload_lds16(A + a_base + (size_t)aRow[i] * KK + ko + aGs[i] * 8,
                  &lds[(t + 256 * i) * 8]);
#pragma unroll
    for (int i = 0; i < BLD; ++i)
      gload_lds16(Bw + b_base + (size_t)bRow[i] * KK + ko + bGs[i] * 8,
                  &lds[8192 + (t + 256 * i) * 8]);
    __syncthreads();   // drains vmcnt -> tile kt fully in LDS

#pragma unroll
    for (int kk = 0; kk < 2; ++kk) {
      const int sg = kk * 4 + lg;
      bf16x8 af[4], bfv[NFR];
#pragma unroll
      for (int i = 0; i < 4; ++i) {
        int R = wr * 64 + i * 16 + lq;
        af[i] = *reinterpret_cast<const bf16x8*>(&lds[(R * 8 + (sg ^ (R & 7))) * 8]);
      }
#pragma unroll
      for (int j = 0; j < NFR; ++j) {
        int R = wc * (BN / 2) + j * 16 + lq;
        bfv[j] = *reinterpret_cast<const bf16x8*>(&lds[8192 + (R * 8 + (sg ^ (R & 7))) * 8]);
      }
#pragma unroll
      for (int i = 0; i < 4; ++i)
#pragma unroll
        for (int j = 0; j < NFR; ++j)
          acc[i][j] = __builtin_amdgcn_mfma_f32_16x16x32_bf16(af[i], bfv[j], acc[i][j], 0, 0, 0);
    }
    __syncthreads();   // all reads of the buffer done before next stage (WAR)
  }

  // epilogue: C/D layout col = lane&15, row = (lane>>4)*4 + reg  (m89-verified)
#pragma unroll
  for (int i = 0; i < 4; ++i) {
#pragma unroll
    for (int j = 0; j < NFR; ++j) {
#pragma unroll
      for (int r = 0; r < 4; ++r) {
        int m = rb * 128 + wr * 64 + i * 16 + lg * 4 + r;
        int n = cb * BN + wc * (BN / 2) + j * 16 + lq;
        float v = acc[i][j][r];
        if (EPI == 0) {
          int which = n >> 10;
          int h = (n >> 6) & 15;
          int d = n & 63;
          int b = m >> 11;
          int tt = m & 2047;
          int bh = b * H_NUM + h;
          if (which == 0) {
            // fold softmax scale AND log2(e) so attention uses exp2 directly
            q_ws[((size_t)bh * T_SEQ + tt) * H_D + d] = f2bf(v * 0.18033688f);
          } else if (which == 1) {
            k_ws[((size_t)bh * T_SEQ + tt) * H_D + d] = f2bf(v);
          } else {
            // V transposed [BH,D,T'] with per-64-tile k-permutation matching
            // the swapped-QK^T in-register P layout (bijective bit shuffle)
            int k0 = tt & 63;
            int tp = (tt & ~63) | ((k0 & 12) << 1) | ((k0 & 48) >> 3) | (k0 & 1) | ((k0 & 2) << 4);
            v_ws[((size_t)bh * H_D + d) * T_SEQ + tp] = f2bf(v);
          }
        } else {
          outf[(size_t)m * 1024 + n] = v;
        }
      }
    }
  }
}

// ---------------------------------------------------------------- flash attention
// (unchanged -- counted-vmcnt 3-buffer pipeline, swapped QK^T in-lane softmax)
__global__ __launch_bounds__(256, 2) void attn_kernel(
    const unsigned short* __restrict__ qw,
    const unsigned short* __restrict__ kw,
    const unsigned short* __restrict__ vtw,
    unsigned short* __restrict__ yw) {
  __shared__ unsigned short kv_lds[3][8192];   // 3 bufs x (K 4096 | V 4096 shorts) = 48KB

  const int bid = blockIdx.x;
  const int bh = (bid & 7) * 8 + ((bid >> 3) & 7);
  const int qblk = bid >> 6;                    // 0..7, 256 rows each

  const int t = threadIdx.x;
  const int w = t >> 6, l = t & 63;
  const int lq = l & 15, lg = l >> 4;
  const int qbase = qblk * 256 + w * 64;
  const size_t head_off = (size_t)bh * T_SEQ * H_D;

  bf16x8 aq[4][2];
#pragma unroll
  for (int qg = 0; qg < 4; ++qg)
#pragma unroll
    for (int kk = 0; kk < 2; ++kk)
      aq[qg][kk] = *reinterpret_cast<const bf16x8*>(
          qw + head_off + (size_t)(qbase + qg * 16 + lq) * H_D + kk * 32 + lg * 8);

  const unsigned short* sbase[4];
  int sstep[4];
#pragma unroll
  for (int i = 0; i < 4; ++i) {
    int c = w * 64 + l + 256 * i;
    if (c < 512) {
      int row = c >> 3, sl = (c & 7) ^ (row & 7);
      sbase[i] = kw + head_off + row * H_D + sl * 8;
      sstep[i] = 64 * H_D;
    } else {
      int c2 = c - 512;
      int row = c2 >> 3, sl = (c2 & 7) ^ (row & 7);
      sbase[i] = vtw + head_off + (size_t)row * T_SEQ + sl * 8;
      sstep[i] = 64;
    }
  }

  unsigned short* bA = &kv_lds[0][0];
  unsigned short* bB = &kv_lds[1][0];
  unsigned short* bC = &kv_lds[2][0];

#define STAGE(KV, DST)                                                              \
  { _Pragma("unroll")                                                               \
    for (int i = 0; i < 4; ++i)                                                     \
      gload_lds16(sbase[i] + (size_t)(KV) * sstep[i], (DST) + (w * 64 + 256 * i) * 8); }

  STAGE(0, bA)
  STAGE(1, bB)

  f32x4 y[4][4] = {};
  float lrow[4] = {0.f, 0.f, 0.f, 0.f};
  union pa_t { bf16x8 v; unsigned int u[4]; };

  for (int kv = 0; kv < T_SEQ / 64; ++kv) {
    if (kv == T_SEQ / 64 - 1) {
      asm volatile("s_waitcnt vmcnt(0)" ::: "memory");
    } else {
      asm volatile("s_waitcnt vmcnt(4)" ::: "memory");
    }
    __builtin_amdgcn_s_barrier();

    bf16x8 kf[8], vf[8];
#pragma unroll
    for (int f = 0; f < 8; ++f) {
      int row = (f >> 1) * 16 + lq;
      int sl = ((f & 1) * 4 + lg) ^ (lq & 7);
      kf[f] = *reinterpret_cast<const bf16x8*>(bA + row * 64 + sl * 8);
    }
#pragma unroll
    for (int db = 0; db < 4; ++db)
#pragma unroll
      for (int ks = 0; ks < 2; ++ks) {
        int row = db * 16 + lq;
        int sl = (ks * 4 + lg) ^ (lq & 7);
        vf[db * 2 + ks] = *reinterpret_cast<const bf16x8*>(bA + 4096 + row * 64 + sl * 8);
      }

    pa_t pa0[4], pa1[4];
#pragma unroll
    for (int qg = 0; qg < 4; ++qg) {
      f32x4 s[4];
#pragma unroll
      for (int tt = 0; tt < 4; ++tt) {
        f32x4 z = {0.f, 0.f, 0.f, 0.f};
        s[tt] = __builtin_amdgcn_mfma_f32_16x16x32_bf16(kf[tt * 2], aq[qg][0], z, 0, 0, 0);
        s[tt] = __builtin_amdgcn_mfma_f32_16x16x32_bf16(kf[tt * 2 + 1], aq[qg][1], s[tt], 0, 0, 0);
      }
      float acc_e = 0.f;
#pragma unroll
      for (int tt = 0; tt < 4; ++tt) {
        float e0 = __builtin_amdgcn_exp2f(s[tt][0]);
        float e1 = __builtin_amdgcn_exp2f(s[tt][1]);
        float e2 = __builtin_amdgcn_exp2f(s[tt][2]);
        float e3 = __builtin_amdgcn_exp2f(s[tt][3]);
        pa0[qg].u[tt] = pack_hi(e0, e1);
        pa1[qg].u[tt] = pack_hi(e2, e3);
        acc_e += (e0 + e1) + (e2 + e3);
      }
      lrow[qg] += acc_e;
    }

#pragma unroll
    for (int qg = 0; qg < 4; ++qg)
#pragma unroll
      for (int db = 0; db < 4; ++db) {
        y[qg][db] = __builtin_amdgcn_mfma_f32_16x16x32_bf16(pa0[qg].v, vf[db * 2], y[qg][db], 0, 0, 0);
        y[qg][db] = __builtin_amdgcn_mfma_f32_16x16x32_bf16(pa1[qg].v, vf[db * 2 + 1], y[qg][db], 0, 0, 0);
      }

    if (kv + 2 < T_SEQ / 64) STAGE(kv + 2, bC)

    unsigned short* tmp = bA; bA = bB; bB = bC; bC = tmp;
  }
#undef STAGE

  const int b = bh >> 4, h = bh & 15;
#pragma unroll
  for (int qg = 0; qg < 4; ++qg) {
    float sm = lrow[qg];
    sm += __shfl_xor(sm, 16);
    sm += __shfl_xor(sm, 32);
    float inv = 1.0f / sm;
#pragma unroll
    for (int r = 0; r < 4; ++r) {
      float iv = __shfl(inv, lg * 4 + r);
      int row = qbase + qg * 16 + lg * 4 + r;
#pragma unroll
      for (int db = 0; db < 4; ++db) {
        int d = db * 16 + lq;
        yw[((size_t)(b * T_SEQ + row)) * C_DIM + h * 64 + d] = f2bf(y[qg][db][r] * iv);
      }
    }
  }
}

// ---------------------------------------------------------------- launch
extern "C" void kernel_launch(void* const* d_in, const int* in_sizes, int n_in,
                              void* d_out, int out_size, void* d_ws, size_t ws_size,
                              hipStream_t stream) {
  (void)in_sizes; (void)n_in; (void)out_size; (void)ws_size;
  const float* x      = (const float*)d_in[0];
  const float* w_attn = (const float*)d_in[1];
  const float* w_proj = (const float*)d_in[2];
  float* out = (float*)d_out;

  unsigned short* ws = (unsigned short*)d_ws;
  const size_t XB = (size_t)M_ROWS * C_DIM;          // 8,388,608
  unsigned short* xb  = ws;                          // x bf16 [8192,1024]; reused as y after attn
  unsigned short* wab = xb + XB;                     // w_attn bf16 [3072,1024]
  unsigned short* wpb = wab + (size_t)3072 * 1024;   // w_proj bf16 [1024,1024]
  unsigned short* qws = wpb + (size_t)1024 * 1024;   // q [BH,T,D] (pre-scaled by 0.125*log2e)
  unsigned short* kws = qws + XB;                    // k [BH,T,D]
  unsigned short* vws = kws + XB;                    // v^T [BH,D,T'] k-permuted
  unsigned short* yws = xb;                          // attention output [B,T,C] (xb dead by then)

  cast_all_kernel<<<3145728 / 256, 256, 0, stream>>>(x, w_attn, w_proj, xb, wab, wpb);

  gemm_bt_kernel<0><<<2048, 256, 0, stream>>>(xb, wab, qws, kws, vws, nullptr);
  attn_kernel<<<512, 256, 0, stream>>>(qws, kws, vws, yws);
  gemm_bt_kernel<1><<<512, 256, 0, stream>>>(yws, wpb, nullptr, nullptr, nullptr, out);
}